// Round 1
// 200.023 us; speedup vs baseline: 1.0383x; 1.0383x over previous
//
#include <hip/hip_runtime.h>

#define BATCH   8
#define LENGTH  4096
#define IN_DIM  512
#define STATE   256
#define OUT_DIM 512
#define NC      64
#define LC      64

typedef __attribute__((ext_vector_type(8))) short bf16x8;
typedef __attribute__((ext_vector_type(4))) float f32x4;

union FragU { bf16x8 v; unsigned u[4]; };

__device__ __forceinline__ unsigned short bf16_rne(float v) {
    unsigned u = __builtin_bit_cast(unsigned, v);
    unsigned r = (u + 0x7FFFu + ((u >> 16) & 1u)) >> 16;
    return (unsigned short)r;
}
__device__ __forceinline__ float bf16_f(unsigned short h) {
    unsigned u = ((unsigned)h) << 16;
    return __builtin_bit_cast(float, u);
}

// ---------------------------------------------------------------------------
// Merged weight split+transpose: B[512][256] and C[256][512] fp32 ->
// hi/lo bf16 planes [N][K] (RNE). One launch instead of two.
// ---------------------------------------------------------------------------
__global__ __launch_bounds__(256) void split_weights(
    const float* __restrict__ B, const float* __restrict__ C,
    unsigned short* __restrict__ Bhi, unsigned short* __restrict__ Blo,
    unsigned short* __restrict__ Chi, unsigned short* __restrict__ Clo)
{
    int id = blockIdx.x * 256 + threadIdx.x;
    if (id < IN_DIM * STATE) {
        int k = id & (IN_DIM - 1), n = id >> 9;      // Bt[n=state][k=in]
        float v = B[(size_t)k * STATE + n];
        unsigned short h = bf16_rne(v);
        Bhi[id] = h;
        Blo[id] = bf16_rne(v - bf16_f(h));
    } else {
        int id2 = id - IN_DIM * STATE;
        int k = id2 & (STATE - 1), n = id2 >> 8;     // Ct[n=out][k=state]
        float v = C[(size_t)k * OUT_DIM + n];
        unsigned short h = bf16_rne(v);
        Chi[id2] = h;
        Clo[id2] = bf16_rne(v - bf16_f(h));
    }
}

// ---------------------------------------------------------------------------
// GEMM1: split-bf16 MFMA GEMM, A read as fp32 (in-register hi/lo split):
//   C[M][N] = A[M][K] (fp32) * Bt[N][K] (pre-split hi/lo bf16 planes)
//   acc += Ahi*Bhi + Alo*Bhi + Ahi*Blo   (fp32 accumulate)
// Block: 512 thr = 8 waves, tile 128x128, BK=32.
// Wave layout 4Mx2N (wave>>1 -> M group of 32 rows, wave&1 -> N half):
// A elements split by only 2 waves (was 4) -> halves the fp32->bf16 VALU.
// ds_read count/wave unchanged (A 2x2 + B 4x2 = 12 x b128).
// LDS double-buffered (2 x 32KB): per buffer A fp32 16KB + Bhi 8KB + Blo 8KB.
// K-loop uses raw s_barrier + manual s_waitcnt vmcnt(4): prefetch for iter
// t+1 stays in flight across the barrier (no vmcnt(0) drain).
// A LDS layout: row = 128B = 8 slots of 16B; phys slot = l ^ (row&7).
// B LDS layout: row = 64B = 4 slots; phys = l ^ ((row>>1)&3).
// Staging inverts the swizzle on the GLOBAL address side so the LDS dst is
// wave-uniform-base + lane*16 (global_load_lds requirement).
// ---------------------------------------------------------------------------
__global__ __launch_bounds__(512, 4) void gemm_dbuf(
    const float* __restrict__ Af, const unsigned short* __restrict__ Bthi,
    const unsigned short* __restrict__ Btlo, float* __restrict__ Cc,
    int N_, int K)
{
    __shared__ unsigned short lds[2 * 16384];   // 64 KB

    const int tid  = threadIdx.x;
    const int wave = tid >> 6;
    const int lane = tid & 63;
    const int n0 = blockIdx.x * 128;
    const int m0 = blockIdx.y * 128;

    // --- staging descriptors: 32 wave-instructions of 1KB; 4 per wave ---
    const char* gp[4];
    int ldsoff[4], gstep[4];
    #pragma unroll
    for (int t = 0; t < 4; ++t) {
        int gi = wave * 4 + t;
        if (gi < 16) {          // A plane: 1024 slots (16 KB)
            int p = gi * 64 + lane;
            int row = p >> 3, s = p & 7;
            int l = s ^ (row & 7);
            gp[t] = (const char*)(Af + (size_t)(m0 + row) * K + l * 4);
            gstep[t] = 32 * 4;              // BK fp32
            ldsoff[t] = gi * 512;
        } else {                // B planes: 512 slots each (8 KB)
            int q2 = (gi - 16) >> 3;        // 0 = hi, 1 = lo
            int pi = gi & 7;
            int p = pi * 64 + lane;
            int row = p >> 2, s = p & 3;
            int l = s ^ ((row >> 1) & 3);
            const unsigned short* base = q2 ? Btlo : Bthi;
            gp[t] = (const char*)(base + (size_t)(n0 + row) * K + l * 8);
            gstep[t] = 32 * 2;              // BK bf16
            ldsoff[t] = 8192 + q2 * 4096 + pi * 512;
        }
    }

    const int r = lane & 15, q = lane >> 4;
    const int wm = (wave >> 1) * 32, wn = (wave & 1) * 64;

    // fragment read offsets (ushort units, within one buffer)
    int aoff[2][2], boff[4];
    #pragma unroll
    for (int i = 0; i < 2; ++i) {
        int row = wm + i * 16 + r;
        #pragma unroll
        for (int h = 0; h < 2; ++h)
            aoff[i][h] = row * 64 + ((2 * q + h) ^ (row & 7)) * 8;
    }
    #pragma unroll
    for (int j = 0; j < 4; ++j) {
        int row = wn + j * 16 + r;
        boff[j] = row * 32 + (q ^ ((row >> 1) & 3)) * 8;
    }

    f32x4 acc[2][4];
    #pragma unroll
    for (int i = 0; i < 2; ++i)
        #pragma unroll
        for (int j = 0; j < 4; ++j)
            acc[i][j] = (f32x4){0.f, 0.f, 0.f, 0.f};

    // prologue: stage buffer 0
    #pragma unroll
    for (int t = 0; t < 4; ++t) {
        __builtin_amdgcn_global_load_lds(
            (const __attribute__((address_space(1))) unsigned*)(gp[t]),
            (__attribute__((address_space(3))) unsigned*)(&lds[ldsoff[t]]),
            16, 0, 0);
        gp[t] += gstep[t];
    }

    const int nit = K >> 5;
    for (int it = 0; it < nit; ++it) {
        // barrier 1: everyone done computing on the buffer we're about to fill
        asm volatile("" ::: "memory");
        __builtin_amdgcn_s_barrier();
        asm volatile("" ::: "memory");
        if (it + 1 < nit) {
            const int bb = ((it + 1) & 1) * 16384;
            #pragma unroll
            for (int t = 0; t < 4; ++t) {
                __builtin_amdgcn_global_load_lds(
                    (const __attribute__((address_space(1))) unsigned*)(gp[t]),
                    (__attribute__((address_space(3))) unsigned*)(&lds[bb + ldsoff[t]]),
                    16, 0, 0);
                gp[t] += gstep[t];
            }
            __builtin_amdgcn_s_waitcnt(0x0F74);   // vmcnt(4): current buf done, prefetch flying
        } else {
            __builtin_amdgcn_s_waitcnt(0x0F70);   // vmcnt(0)
        }
        asm volatile("" ::: "memory");
        __builtin_amdgcn_s_barrier();             // barrier 2: current buf visible to all
        asm volatile("" ::: "memory");

        const unsigned short* buf = &lds[(it & 1) * 16384];

        // A fragments: fp32 -> hi/lo bf16 (trunc split, v_perm packing)
        FragU ahi[2], alo[2];
        #pragma unroll
        for (int i = 0; i < 2; ++i) {
            #pragma unroll
            for (int h = 0; h < 2; ++h) {
                float4 f = *(const float4*)(buf + aoff[i][h]);
                unsigned bx = __builtin_bit_cast(unsigned, f.x);
                unsigned by = __builtin_bit_cast(unsigned, f.y);
                unsigned bz = __builtin_bit_cast(unsigned, f.z);
                unsigned bw = __builtin_bit_cast(unsigned, f.w);
                ahi[i].u[h * 2]     = __builtin_amdgcn_perm(by, bx, 0x07060302);
                ahi[i].u[h * 2 + 1] = __builtin_amdgcn_perm(bw, bz, 0x07060302);
                float lx = f.x - __builtin_bit_cast(float, bx & 0xFFFF0000u);
                float ly = f.y - __builtin_bit_cast(float, by & 0xFFFF0000u);
                float lz = f.z - __builtin_bit_cast(float, bz & 0xFFFF0000u);
                float lw = f.w - __builtin_bit_cast(float, bw & 0xFFFF0000u);
                alo[i].u[h * 2]     = __builtin_amdgcn_perm(
                    __builtin_bit_cast(unsigned, ly), __builtin_bit_cast(unsigned, lx), 0x07060302);
                alo[i].u[h * 2 + 1] = __builtin_amdgcn_perm(
                    __builtin_bit_cast(unsigned, lw), __builtin_bit_cast(unsigned, lz), 0x07060302);
            }
        }
        FragU bhi[4], blo[4];
        #pragma unroll
        for (int j = 0; j < 4; ++j) {
            bhi[j].v = *(const bf16x8*)(buf +  8192 + boff[j]);
            blo[j].v = *(const bf16x8*)(buf + 12288 + boff[j]);
        }
        #pragma unroll
        for (int i = 0; i < 2; ++i)
            #pragma unroll
            for (int j = 0; j < 4; ++j) {
                acc[i][j] = __builtin_amdgcn_mfma_f32_16x16x32_bf16(ahi[i].v, bhi[j].v, acc[i][j], 0, 0, 0);
                acc[i][j] = __builtin_amdgcn_mfma_f32_16x16x32_bf16(alo[i].v, bhi[j].v, acc[i][j], 0, 0, 0);
                acc[i][j] = __builtin_amdgcn_mfma_f32_16x16x32_bf16(ahi[i].v, blo[j].v, acc[i][j], 0, 0, 0);
            }
    }

    // epilogue: C/D layout col = lane&15, row = q*4 + reg
    #pragma unroll
    for (int i = 0; i < 2; ++i) {
        #pragma unroll
        for (int reg = 0; reg < 4; ++reg) {
            int mg = m0 + wm + i * 16 + q * 4 + reg;
            float* dst = Cc + (size_t)mg * N_ + n0 + wn + r;
            dst[0]  = acc[i][0][reg];
            dst[16] = acc[i][1][reg];
            dst[32] = acc[i][2][reg];
            dst[48] = acc[i][3][reg];
        }
    }
}

// ---------------------------------------------------------------------------
// GEMM2: all operands pre-split bf16 planes (A = x emitted by scan_apply):
//   C[M][N] = A[M][K] * Bt[N][K],  acc += Ahi*Bhi + Alo*Bhi + Ahi*Blo
// No in-register fp32 split at all: A fragments are direct ds_read_b128,
// same verified swizzle/staging as the B path. Per buffer: Ahi/Alo/Bhi/Blo
// 8KB each = 32KB; double-buffered 64KB. Same barrier/vmcnt(4) schedule.
// Wave layout 2Mx4N (wm=(wave>>2)*64, wn=(wave&3)*32); 12 ds_read/wave.
// ---------------------------------------------------------------------------
__global__ __launch_bounds__(512, 4) void gemm_presplit(
    const unsigned short* __restrict__ Athi, const unsigned short* __restrict__ Atlo,
    const unsigned short* __restrict__ Bthi, const unsigned short* __restrict__ Btlo,
    float* __restrict__ Cc, int N_, int K)
{
    __shared__ unsigned short lds[2 * 16384];   // 64 KB

    const int tid  = threadIdx.x;
    const int wave = tid >> 6;
    const int lane = tid & 63;
    const int n0 = blockIdx.x * 128;
    const int m0 = blockIdx.y * 128;

    // --- staging: 4 planes x 8KB = 32 chunks of 1KB; 4 per wave, plane = wave>>1
    const char* gp[4];
    int ldsoff[4];
    #pragma unroll
    for (int t = 0; t < 4; ++t) {
        int gi = wave * 4 + t;
        int plane = gi >> 3;                // 0=Ahi 1=Alo 2=Bhi 3=Blo (wave-uniform)
        int pi = gi & 7;
        int p = pi * 64 + lane;
        int row = p >> 2, s = p & 3;
        int l = s ^ ((row >> 1) & 3);
        const unsigned short* base =
            (plane == 0) ? Athi : (plane == 1) ? Atlo : (plane == 2) ? Bthi : Btlo;
        int r0 = (plane < 2) ? m0 : n0;
        gp[t] = (const char*)(base + (size_t)(r0 + row) * K + l * 8);
        ldsoff[t] = plane * 4096 + pi * 512;
    }

    const int r = lane & 15, q = lane >> 4;
    const int wm = (wave >> 2) * 64, wn = (wave & 3) * 32;

    int aoff[4], boff[2];
    #pragma unroll
    for (int i = 0; i < 4; ++i) {
        int row = wm + i * 16 + r;
        aoff[i] = row * 32 + (q ^ ((row >> 1) & 3)) * 8;
    }
    #pragma unroll
    for (int j = 0; j < 2; ++j) {
        int row = wn + j * 16 + r;
        boff[j] = row * 32 + (q ^ ((row >> 1) & 3)) * 8;
    }

    f32x4 acc[4][2];
    #pragma unroll
    for (int i = 0; i < 4; ++i)
        #pragma unroll
        for (int j = 0; j < 2; ++j)
            acc[i][j] = (f32x4){0.f, 0.f, 0.f, 0.f};

    // prologue: stage buffer 0
    #pragma unroll
    for (int t = 0; t < 4; ++t) {
        __builtin_amdgcn_global_load_lds(
            (const __attribute__((address_space(1))) unsigned*)(gp[t]),
            (__attribute__((address_space(3))) unsigned*)(&lds[ldsoff[t]]),
            16, 0, 0);
        gp[t] += 64;                        // BK bf16 = 64 B
    }

    const int nit = K >> 5;
    for (int it = 0; it < nit; ++it) {
        asm volatile("" ::: "memory");
        __builtin_amdgcn_s_barrier();
        asm volatile("" ::: "memory");
        if (it + 1 < nit) {
            const int bb = ((it + 1) & 1) * 16384;
            #pragma unroll
            for (int t = 0; t < 4; ++t) {
                __builtin_amdgcn_global_load_lds(
                    (const __attribute__((address_space(1))) unsigned*)(gp[t]),
                    (__attribute__((address_space(3))) unsigned*)(&lds[bb + ldsoff[t]]),
                    16, 0, 0);
                gp[t] += 64;
            }
            __builtin_amdgcn_s_waitcnt(0x0F74);   // vmcnt(4)
        } else {
            __builtin_amdgcn_s_waitcnt(0x0F70);   // vmcnt(0)
        }
        asm volatile("" ::: "memory");
        __builtin_amdgcn_s_barrier();
        asm volatile("" ::: "memory");

        const unsigned short* buf = &lds[(it & 1) * 16384];

        FragU ahi[4], alo[4];
        #pragma unroll
        for (int i = 0; i < 4; ++i) {
            ahi[i].v = *(const bf16x8*)(buf +        aoff[i]);
            alo[i].v = *(const bf16x8*)(buf + 4096 + aoff[i]);
        }
        FragU bhi[2], blo[2];
        #pragma unroll
        for (int j = 0; j < 2; ++j) {
            bhi[j].v = *(const bf16x8*)(buf +  8192 + boff[j]);
            blo[j].v = *(const bf16x8*)(buf + 12288 + boff[j]);
        }
        #pragma unroll
        for (int i = 0; i < 4; ++i)
            #pragma unroll
            for (int j = 0; j < 2; ++j) {
                acc[i][j] = __builtin_amdgcn_mfma_f32_16x16x32_bf16(ahi[i].v, bhi[j].v, acc[i][j], 0, 0, 0);
                acc[i][j] = __builtin_amdgcn_mfma_f32_16x16x32_bf16(alo[i].v, bhi[j].v, acc[i][j], 0, 0, 0);
                acc[i][j] = __builtin_amdgcn_mfma_f32_16x16x32_bf16(ahi[i].v, blo[j].v, acc[i][j], 0, 0, 0);
            }
    }

    // epilogue: C/D layout col = lane&15, row = q*4 + reg
    #pragma unroll
    for (int i = 0; i < 4; ++i) {
        #pragma unroll
        for (int reg = 0; reg < 4; ++reg) {
            int mg = m0 + wm + i * 16 + q * 4 + reg;
            float* dst = Cc + (size_t)mg * N_ + n0 + wn + r;
            dst[0]  = acc[i][0][reg];
            dst[16] = acc[i][1][reg];
        }
    }
}

// ---------------------------------------------------------------------------
// Scan phase A: per-chunk carry with zero initial state.
// ---------------------------------------------------------------------------
__global__ __launch_bounds__(256) void scan_carry(
    const float* __restrict__ uB, const float* __restrict__ A,
    float* __restrict__ carry)
{
    const int b = blockIdx.x;
    const int c = blockIdx.y;
    const int n = threadIdx.x;
    const float a = A[n];
    const float* p = uB + ((size_t)b * LENGTH + (size_t)c * LC) * STATE + n;
    float s = 0.f;
    #pragma unroll 8
    for (int j = 0; j < LC; ++j) s = a * s + p[(size_t)j * STATE];
    carry[((size_t)b * NC + c) * STATE + n] = s;
}

// ---------------------------------------------------------------------------
// Scan phase B (fused combine+apply): block (b,c) rebuilds its entry state
// from the carries, then re-applies the recurrence. Output x is written
// directly as TRUNC-split hi/lo bf16 planes (bit-identical to the split
// GEMM2 used to do in-register) -> GEMM2 needs no fp32 split at all.
// Last chunk also writes x_last fp32.
// ---------------------------------------------------------------------------
__global__ __launch_bounds__(256) void scan_apply(
    const float* __restrict__ uB, const float* __restrict__ A,
    const float* __restrict__ carry, const float* __restrict__ x0,
    unsigned short* __restrict__ xhi, unsigned short* __restrict__ xlo,
    float* __restrict__ x_last)
{
    const int b = blockIdx.x;
    const int c = blockIdx.y;
    const int n = threadIdx.x;
    const float a = A[n];
    float a2 = a * a, a4 = a2 * a2, a8 = a4 * a4, a16 = a8 * a8, a32 = a16 * a16;
    const float aLC = a32 * a32;   // a^64

    float s = x0[(size_t)b * STATE + n];
    for (int d = 0; d < c; ++d)
        s = aLC * s + carry[((size_t)b * NC + d) * STATE + n];

    const size_t base = ((size_t)b * LENGTH + (size_t)c * LC) * STATE + n;
    const float* p = uB + base;
    unsigned short* qh = xhi + base;
    unsigned short* ql = xlo + base;
    #pragma unroll 8
    for (int j = 0; j < LC; ++j) {
        s = a * s + p[(size_t)j * STATE];
        unsigned u = __builtin_bit_cast(unsigned, s);
        qh[(size_t)j * STATE] = (unsigned short)(u >> 16);
        float lo = s - __builtin_bit_cast(float, u & 0xFFFF0000u);
        ql[(size_t)j * STATE] = (unsigned short)(__builtin_bit_cast(unsigned, lo) >> 16);
    }
    if (c == NC - 1) x_last[(size_t)b * STATE + n] = s;
}

// ---------------------------------------------------------------------------
extern "C" void kernel_launch(void* const* d_in, const int* in_sizes, int n_in,
                              void* d_out, int out_size, void* d_ws, size_t ws_size,
                              hipStream_t stream)
{
    const float* u  = (const float*)d_in[0];   // [8,4096,512]
    const float* x0 = (const float*)d_in[1];   // [8,256]
    const float* A  = (const float*)d_in[2];   // [256]
    const float* B  = (const float*)d_in[3];   // [512,256]
    const float* C  = (const float*)d_in[4];   // [256,512]

    const size_t MB = 1024 * 1024;
    char* ws = (char*)d_ws;

    unsigned short* xhi = (unsigned short*)(ws);                // [M,256] bf16, 16 MB
    unsigned short* xlo = (unsigned short*)(ws + 16 * MB);      // [M,256] bf16, 16 MB
    float* carry = (float*)(ws + 32 * MB);                      // 512 KB
    unsigned short* Bt_hi = (unsigned short*)(ws + 33 * MB);                // 256 KB
    unsigned short* Bt_lo = (unsigned short*)(ws + 33 * MB + 256 * 1024);   // 256 KB
    unsigned short* Ct_hi = (unsigned short*)(ws + 33 * MB + 512 * 1024);   // 256 KB
    unsigned short* Ct_lo = (unsigned short*)(ws + 33 * MB + 768 * 1024);   // 256 KB

    float* y      = (float*)d_out;                             // [8,4096,512] = 64 MB
    float* x_last = y + (size_t)BATCH * LENGTH * OUT_DIM;      // [8,256]
    // uB parks in the upper half of y's region; dead before GEMM2 writes y.
    float* uB     = (float*)((char*)d_out + 32 * MB);          // [M,256] = 32 MB

    const int M = BATCH * LENGTH;   // 32768

    // 1. split+transpose both weights to bf16 hi/lo planes (one launch)
    split_weights<<<dim3((IN_DIM * STATE + STATE * OUT_DIM) / 256), dim3(256), 0, stream>>>(
        B, C, Bt_hi, Bt_lo, Ct_hi, Ct_lo);

    // 2. GEMM1: uB[M,256] = u[M,512] @ B  (A fp32 direct, split in-register)
    gemm_dbuf<<<dim3(STATE / 128, M / 128), dim3(512), 0, stream>>>(
        u, Bt_hi, Bt_lo, uB, STATE, IN_DIM);

    // 3. chunked scan (fp32 exact); apply emits x as pre-split bf16 planes
    scan_carry<<<dim3(BATCH, NC), dim3(256), 0, stream>>>(uB, A, carry);
    scan_apply<<<dim3(BATCH, NC), dim3(256), 0, stream>>>(uB, A, carry, x0, xhi, xlo, x_last);

    // 4. GEMM2: y[M,512] = x[M,256] @ C  (all operands pre-split bf16)
    gemm_presplit<<<dim3(OUT_DIM / 128, M / 128), dim3(512), 0, stream>>>(
        xhi, xlo, Ct_hi, Ct_lo, y, OUT_DIM, STATE);
}